// Round 9
// baseline (1271.744 us; speedup 1.0000x reference)
//
#include <hip/hip_runtime.h>
#include <hip/hip_fp16.h>

#define B_ 4096
#define T_ 64
#define NROWS (B_*T_)      // 262144
#define BLOB_B 2099200     // byte offset of weight blob in ws
#define JD_REL 163840      // jd_w1 K=256 image offset WITHIN blob (64 KB)
#define PIMG_B (BLOB_B + 229376)      // param image (4 KB f16), absolute in ws

typedef _Float16 f16x8 __attribute__((ext_vector_type(8)));
typedef float    f32x4 __attribute__((ext_vector_type(4)));

__device__ __forceinline__ float gelu_f(float x){
    return 0.5f * x * (1.0f + erff(x * 0.70710678118654752f));
}

// ---------- async global->LDS, 16B per lane, linear dest ----------
__device__ __forceinline__ void gll16(const void* g, void* l){
    __builtin_amdgcn_global_load_lds(
        (const __attribute__((address_space(1))) void*)g,
        (__attribute__((address_space(3))) void*)l, 16, 0, 0);
}

// stage 32KB image (4 waves x 8 x 1KB)
__device__ __forceinline__ void stage_w32(const char* gsrc, char* dst, int wave, int lane){
    const char* g = gsrc + wave * 8192 + lane * 16;
    char* l = dst + wave * 8192;
#pragma unroll
    for (int r = 0; r < 8; r++) gll16(g + r * 1024, l + r * 1024);
}

// stage 4KB param image
__device__ __forceinline__ void stage_p(const char* gsrc, char* dst, int wave, int lane){
    gll16(gsrc + wave * 1024 + lane * 16, dst + wave * 1024);
}

// ---------- input rows -> f16 A-fragments (K=128 -> 4 frags)
__device__ __forceinline__ void load_in(f16x8* a, const float* __restrict__ p, int g){
#pragma unroll
    for (int ks = 0; ks < 4; ks++){
        const float* q = p + ks * 32 + g * 8;
        float4 v0 = *(const float4*)q, v1 = *(const float4*)(q + 4);
        f16x8 t;
        t[0]=(_Float16)v0.x; t[1]=(_Float16)v0.y; t[2]=(_Float16)v0.z; t[3]=(_Float16)v0.w;
        t[4]=(_Float16)v1.x; t[5]=(_Float16)v1.y; t[6]=(_Float16)v1.z; t[7]=(_Float16)v1.w;
        a[ks] = t;
    }
}

// ---------- A-fragments from wave-private ab tile [16][128] f16
__device__ __forceinline__ void load_a(f16x8* a, const char* ab, int c, int g){
    const int rswz = (c & 7) << 4;
    const char* rp = ab + c * 256;
#pragma unroll
    for (int ks = 0; ks < 4; ks++)
        a[ks] = *(const f16x8*)(rp + ((ks * 64 + g * 16) ^ rswz));
}

// ---------- 8-tile MFMA, K=128, row stride 256B
__device__ __forceinline__ void mfma_tile(f32x4* acc, const f16x8* a,
                                          const char* wb, int c, int g){
#pragma unroll
    for (int n = 0; n < 8; n++){
        const int r = n * 16 + c;
        const char* rp = wb + r * 256;
        const int swz = (r & 7) << 4;
#pragma unroll
        for (int ks = 0; ks < 4; ks++){
            f16x8 b = *(const f16x8*)(rp + ((ks * 64 + g * 16) ^ swz));
            acc[n] = __builtin_amdgcn_mfma_f32_16x16x32_f16(a[ks], b, acc[n], 0, 0, 0);
        }
    }
}

// ---------- 8-tile MFMA, K=256, row stride 512B (joint decoder)
__device__ __forceinline__ void mfma_tile8(f32x4* acc, const f16x8* a,
                                           const char* wb, int c, int g){
#pragma unroll
    for (int n = 0; n < 8; n++){
        const int r = n * 16 + c;
        const char* rp = wb + r * 512;
        const int swz = (r & 7) << 4;
#pragma unroll
        for (int ks = 0; ks < 8; ks++){
            f16x8 b = *(const f16x8*)(rp + ((ks * 64 + g * 16) ^ swz));
            acc[n] = __builtin_amdgcn_mfma_f32_16x16x32_f16(a[ks], b, acc[n], 0, 0, 0);
        }
    }
}

// ---------- LN'd A-fragments in registers
__device__ __forceinline__ void build_y(f16x8* y, const f16x8* x, float mu, float rs,
                                        const char* sp, int goff, int boff, int g){
#pragma unroll
    for (int ks = 0; ks < 4; ks++){
        f16x8 gam = *(const f16x8*)(sp + goff * 2 + ks * 64 + g * 16);
        f16x8 bet = *(const f16x8*)(sp + boff * 2 + ks * 64 + g * 16);
        f16x8 t;
#pragma unroll
        for (int j = 0; j < 8; j++){
            float v = ((float)x[ks][j] - mu) * rs * (float)gam[j] + (float)bet[j];
            t[j] = (_Float16)v;
        }
        y[ks] = t;
    }
}

// ---------- per-row stats over lane's 32 elems + 4-lane-group reduce
__device__ __forceinline__ void row_stats(const f16x8* x, float& s0, float& s1){
    s0 = 0.f; s1 = 0.f;
#pragma unroll
    for (int ks = 0; ks < 4; ks++)
#pragma unroll
        for (int j = 0; j < 8; j++){ float v = (float)x[ks][j]; s0 += v; s1 += v*v; }
    s0 += __shfl_xor(s0, 16); s0 += __shfl_xor(s0, 32);
    s1 += __shfl_xor(s1, 16); s1 += __shfl_xor(s1, 32);
}

// ---------- logits + CE from C-layout acc (shfl-dot over 16 c-lanes)
__device__ __forceinline__ void logits_ce(const f32x4* acc, const char* sp,
                                          int b1off, int w2off, float b2x, float b2y,
                                          int c, int g, int lab, float* ce){
    const _Float16* sbf = (const _Float16*)sp;
    float l0[4] = {0,0,0,0}, l1[4] = {0,0,0,0};
#pragma unroll
    for (int n = 0; n < 8; n++){
        const int r = n * 16 + c;
        float b1v = (float)sbf[b1off + r];
        float wx  = (float)sbf[w2off + 2 * r];
        float wy  = (float)sbf[w2off + 2 * r + 1];
#pragma unroll
        for (int rr = 0; rr < 4; rr++){
            float hv = gelu_f(acc[n][rr] + b1v);
            l0[rr] += hv * wx; l1[rr] += hv * wy;
        }
    }
#pragma unroll
    for (int rr = 0; rr < 4; rr++){
#pragma unroll
        for (int m = 1; m < 16; m <<= 1){ l0[rr] += __shfl_xor(l0[rr], m); l1[rr] += __shfl_xor(l1[rr], m); }
        float v0 = l0[rr] + b2x, v1 = l1[rr] + b2y;
        float mx = fmaxf(v0, v1);
        float lse = mx + logf(expf(v0 - mx) + expf(v1 - mx));
        ce[rr] = lse - (lab ? v1 : v0);
    }
}

// ---------- MFMA phase with bias(+gelu) epilogue into ab tile
template<bool GELU>
__device__ __forceinline__ void phase_store(const f16x8* a, const char* wb, char* ab,
                                            const char* sp, int boff, int c, int g){
    const _Float16* sbf = (const _Float16*)sp;
    f32x4 acc[8];
#pragma unroll
    for (int n = 0; n < 8; n++) acc[n] = (f32x4){0.f,0.f,0.f,0.f};
    mfma_tile(acc, a, wb, c, g);
#pragma unroll
    for (int n = 0; n < 8; n++){
        const int col = n * 16 + c;
        float bi = (float)sbf[boff + col];
#pragma unroll
        for (int rr = 0; rr < 4; rr++){
            float v = acc[n][rr] + bi;
            if (GELU) v = gelu_f(v);
            int row = g * 4 + rr;
            *(_Float16*)(ab + row * 256 + ((col << 1) ^ ((row & 7) << 4))) = (_Float16)v;
        }
    }
}

// ======================= prep + stats (merged) =============================
__global__ void k_prep(const float* __restrict__ ce_w1, const float* __restrict__ ce_w2,
                       const float* __restrict__ se_w1, const float* __restrict__ se_w2,
                       const float* __restrict__ cd_w1, const float* __restrict__ jd_w1,
                       const float* __restrict__ ce_b1, const float* __restrict__ ce_b2,
                       const float* __restrict__ se_b1, const float* __restrict__ se_b2,
                       const float* __restrict__ cd_g,  const float* __restrict__ cd_bt,
                       const float* __restrict__ cd_b1, const float* __restrict__ jd_g,
                       const float* __restrict__ jd_bt, const float* __restrict__ jd_b1,
                       const float* __restrict__ cd_w2, const float* __restrict__ jd_w2,
                       const int* __restrict__ mask, const int* __restrict__ labels,
                       float* __restrict__ ws){
    char* blob = (char*)ws + BLOB_B;
    const int bid = blockIdx.x, tid = threadIdx.x;
    if (bid < 320){
        // 5 K=128 matrices: ce_w1, ce_w2, se_w1, se_w2, cd_w1
        int e = bid * 256 + tid;
        int m = e >> 14, idx = e & 16383;
        int k = idx >> 7, cc = idx & 127;
        const float* src;
        switch (m){
            case 0: src = ce_w1; break;
            case 1: src = ce_w2; break;
            case 2: src = se_w1; break;
            case 3: src = se_w2; break;
            default: src = cd_w1; break;
        }
        float v = src[k * 128 + cc];
        int byte = m * 32768 + cc * 256 + ((k << 1) ^ ((cc & 7) << 4));
        *(_Float16*)(blob + byte) = (_Float16)v;
    } else if (bid < 448){
        // jd_w1 as single K=256 image, row stride 512B, at blob+JD_REL
        int e = (bid - 320) * 256 + tid;
        int k = e >> 7, cc = e & 127;
        float v = jd_w1[k * 128 + cc];
        int byte = JD_REL + cc * 512 + ((k << 1) ^ ((cc & 7) << 4));
        *(_Float16*)(blob + byte) = (_Float16)v;
    } else if (bid < 512){
        // stats for t = bid-448
        int t = bid - 448;
        float c0 = 0.f, c1 = 0.f;
        for (int b = tid; b < B_; b += 256){
            if (mask[b * T_ + t]){
                if (labels[b] == 1) c1 += 1.f; else c0 += 1.f;
            }
        }
        for (int m = 1; m < 64; m <<= 1){ c0 += __shfl_xor(c0, m); c1 += __shfl_xor(c1, m); }
        __shared__ float sh[8];
        int w = tid >> 6, l = tid & 63;
        if (l == 0){ sh[w] = c0; sh[4 + w] = c1; }
        __syncthreads();
        if (tid == 0){
            float a0 = sh[0] + sh[1] + sh[2] + sh[3];
            float a1 = sh[4] + sh[5] + sh[6] + sh[7];
            float tot = a0 + a1;
            float d = fmaxf(tot, 1.f);
            float p0 = a0 / d, p1 = a1 / d;
            float ent = -(p0 * logf(p0 + 1e-8f) + p1 * logf(p1 + 1e-8f));
            ws[t] = ent;
            ws[64 + t] = (tot >= 2.f) ? 1.f : 0.f;
            ws[128 + t] = tot;
        }
    } else {
        _Float16* p = (_Float16*)((char*)ws + PIMG_B);
        if (tid < 128){
            p[tid]       = (_Float16)ce_b1[tid]; p[128 + tid] = (_Float16)ce_b2[tid];
            p[256 + tid] = (_Float16)se_b1[tid]; p[384 + tid] = (_Float16)se_b2[tid];
            p[512 + tid] = (_Float16)cd_g[tid];  p[640 + tid] = (_Float16)cd_bt[tid];
            p[768 + tid] = (_Float16)cd_b1[tid]; p[896 + tid] = (_Float16)jd_b1[tid];
        } else {
            int i = tid - 128;
            p[1024 + i] = (_Float16)jd_g[i];        p[1152 + i] = (_Float16)jd_g[128 + i];
            p[1280 + i] = (_Float16)jd_bt[i];       p[1408 + i] = (_Float16)jd_bt[128 + i];
            p[1536 + 2*i] = (_Float16)cd_w2[2*i];   p[1537 + 2*i] = (_Float16)cd_w2[2*i+1];
            p[1792 + 2*i] = (_Float16)jd_w2[2*i];   p[1793 + 2*i] = (_Float16)jd_w2[2*i+1];
        }
    }
}

// ======================= main fused kernel =================================
// 256 threads (4 waves), 128 rows/block (2 chunks of 64), grid 2048.
// LDS: one 69632B carve: [0,32K)=wbuf | [32K,64K)=ab tiles | [64K,68K)=params.
// Joint phase uses [0,64K) as a single K=256 jd_w1 image.
__global__ __launch_bounds__(256, 2) void k_main(
    const float* __restrict__ xc, const float* __restrict__ xs,
    const int* __restrict__ labels, const int* __restrict__ mask,
    const float* __restrict__ cd_b2, const float* __restrict__ jd_b2,
    float* __restrict__ ws, float* __restrict__ out)
{
    __shared__ __align__(16) char lds[69632];

    const int tid = threadIdx.x;
    const int wave = tid >> 6, lane = tid & 63;
    const int c = lane & 15, g = lane >> 4;
    const int wrow0 = blockIdx.x * 128 + wave * 16;   // chunk0 rows; chunk1 = +64
    char* const wb  = lds;
    char* const ab0 = lds + 32768 + (wave * 2 + 0) * 4096;
    char* const ab1 = lds + 32768 + (wave * 2 + 1) * 4096;
    const char* sp  = lds + 65536;
    const char* blob = (const char*)ws + BLOB_B;
    const int lab0 = labels[blockIdx.x * 2];
    const int lab1 = labels[blockIdx.x * 2 + 1];
    const float cb2x = cd_b2[0], cb2y = cd_b2[1];
    const float jb2x = jd_b2[0], jb2y = jd_b2[1];

    f16x8 aA[4], aB[4], a4[4], cr[4], cr2[4], sr[4], sr2[4];
    float ceC0[4], ceC1[4], ceJ[4];
    float s0c, s1c, s0c2, s1c2;
    float mc0, rc0, mc1, rc1, jm0, jr0, jm1, jr1;

    // ---- P0: stage params + ce_w1; prefetch xc (both chunks) --------------
    stage_p((const char*)ws + PIMG_B, (char*)sp, wave, lane);
    stage_w32(blob + 0 * 32768, wb, wave, lane);
    load_in(aA, xc + (wrow0 + c) * 128, g);
    load_in(aB, xc + (wrow0 + 64 + c) * 128, g);
    __syncthreads();                                            // B1: ce_w1 ready

    // ---- P1: enc1 causal (both chunks) ------------------------------------
    phase_store<true>(aA, wb, ab0, sp, 0, c, g);
    phase_store<true>(aB, wb, ab1, sp, 0, c, g);
    __syncthreads();                                            // B2: ce_w1 retired
    stage_w32(blob + 1 * 32768, wb, wave, lane);                // ce_w2
    load_in(aA, xs + (wrow0 + c) * 128, g);                     // filler: xs prefetch
    load_in(aB, xs + (wrow0 + 64 + c) * 128, g);
    __syncthreads();                                            // B3: ce_w2 ready

    // ---- P2: enc2 causal -> c_rep tiles -----------------------------------
    load_a(a4, ab0, c, g);
    phase_store<false>(a4, wb, ab0, sp, 128, c, g);
    load_a(a4, ab1, c, g);
    phase_store<false>(a4, wb, ab1, sp, 128, c, g);
    __syncthreads();                                            // B4: ce_w2 retired
    stage_w32(blob + 2 * 32768, wb, wave, lane);                // se_w1
    load_a(cr, ab0, c, g);  row_stats(cr, s0c, s1c);            // fillers
    load_a(cr2, ab1, c, g); row_stats(cr2, s0c2, s1c2);
    __syncthreads();                                            // B5: se_w1 ready

    // ---- P3: enc1 spurious -------------------------------------------------
    phase_store<true>(aA, wb, ab0, sp, 256, c, g);
    phase_store<true>(aB, wb, ab1, sp, 256, c, g);
    __syncthreads();                                            // B6: se_w1 retired
    stage_w32(blob + 3 * 32768, wb, wave, lane);                // se_w2
    __syncthreads();                                            // B7: se_w2 ready

    // ---- P4: enc2 spurious -> s_rep tiles; all stats -----------------------
    load_a(a4, ab0, c, g);
    phase_store<false>(a4, wb, ab0, sp, 384, c, g);
    load_a(a4, ab1, c, g);
    phase_store<false>(a4, wb, ab1, sp, 384, c, g);
    __syncthreads();                                            // B8: se_w2 retired
    stage_w32(blob + 4 * 32768, wb, wave, lane);                // cd_w1
    {
        float s0s, s1s, s0s2, s1s2;
        load_a(sr, ab0, c, g);  row_stats(sr, s0s, s1s);
        load_a(sr2, ab1, c, g); row_stats(sr2, s0s2, s1s2);
        mc0 = s0c  * (1.f/128.f); rc0 = rsqrtf(s1c *(1.f/128.f) - mc0*mc0 + 1e-5f);
        mc1 = s0c2 * (1.f/128.f); rc1 = rsqrtf(s1c2*(1.f/128.f) - mc1*mc1 + 1e-5f);
        jm0 = (s0c + s0s)   * (1.f/256.f); jr0 = rsqrtf((s1c + s1s)  *(1.f/256.f) - jm0*jm0 + 1e-5f);
        jm1 = (s0c2 + s0s2) * (1.f/256.f); jr1 = rsqrtf((s1c2 + s1s2)*(1.f/256.f) - jm1*jm1 + 1e-5f);
    }
    __syncthreads();                                            // B9: cd_w1 ready; ab free
    stage_w32(blob + JD_REL + 32768, lds + 32768, wave, lane);  // jd rows 64..127 -> ab region

    // ---- P5: causal decoder (in-reg) + ceC (both chunks) -------------------
    {
        f16x8 yb[4];
        f32x4 acc[8];
        build_y(yb, cr, mc0, rc0, sp, 512, 640, g);
#pragma unroll
        for (int n = 0; n < 8; n++) acc[n] = (f32x4){0.f,0.f,0.f,0.f};
        mfma_tile(acc, yb, wb, c, g);
        logits_ce(acc, sp, 768, 1536, cb2x, cb2y, c, g, lab0, ceC0);
        build_y(yb, cr2, mc1, rc1, sp, 512, 640, g);
#pragma unroll
        for (int n = 0; n < 8; n++) acc[n] = (f32x4){0.f,0.f,0.f,0.f};
        mfma_tile(acc, yb, wb, c, g);
        __syncthreads();                                        // B10: cd_w1 retired, jd-upper landed
        stage_w32(blob + JD_REL, wb, wave, lane);               // jd rows 0..63 -> wbuf
        logits_ce(acc, sp, 768, 1536, cb2x, cb2y, c, g, lab1, ceC1);  // filler
    }
    __syncthreads();                                            // B11: full jd image ready

    // ---- P6: joint decoder (K=256, one pass per chunk) + epilogue ----------
    {
        f16x8 a8[8];
        f32x4 acc[8];
        // chunk 0
        build_y(&a8[0], cr, jm0, jr0, sp, 1024, 1280, g);
        build_y(&a8[4], sr, jm0, jr0, sp, 1152, 1408, g);
#pragma unroll
        for (int n = 0; n < 8; n++) acc[n] = (f32x4){0.f,0.f,0.f,0.f};
        mfma_tile8(acc, a8, lds, c, g);
        logits_ce(acc, sp, 896, 1792, jb2x, jb2y, c, g, lab0, ceJ);
        if (c == 0){
            const int rowbase = wrow0 + g * 4;
            const int4  m4 = *(const int4*)(mask + rowbase);
            const float4 e4 = *(const float4*)(ws + (rowbase & 63));
            const float4 s4 = *(const float4*)(ws + 64 + (rowbase & 63));
            const int   mm[4] = {m4.x, m4.y, m4.z, m4.w};
            const float ee[4] = {e4.x, e4.y, e4.z, e4.w};
            const float sv[4] = {s4.x, s4.y, s4.z, s4.w};
            float rw[4], mcv[4], mjv[4];
#pragma unroll
            for (int rr = 0; rr < 4; rr++){
                float mf = mm[rr] ? 1.f : 0.f;
                float cec = ceC0[rr], cej = ceJ[rr];
                rw[rr]  = mf * sv[rr] * (ee[rr] - cec - 0.5f * fmaxf(cec - cej, 0.f));
                mcv[rr] = mf * cec;  mjv[rr] = mf * cej;
            }
            *(float4*)(out + rowbase)              = (float4){rw[0], rw[1], rw[2], rw[3]};
            *(float4*)(ws + 512 + rowbase)         = (float4){mcv[0], mcv[1], mcv[2], mcv[3]};
            *(float4*)(ws + 512 + NROWS + rowbase) = (float4){mjv[0], mjv[1], mjv[2], mjv[3]};
        }
        // chunk 1
        build_y(&a8[0], cr2, jm1, jr1, sp, 1024, 1280, g);
        build_y(&a8[4], sr2, jm1, jr1, sp, 1152, 1408, g);
#pragma unroll
        for (int n = 0; n < 8; n++) acc[n] = (f32x4){0.f,0.f,0.f,0.f};
        mfma_tile8(acc, a8, lds, c, g);
        logits_ce(acc, sp, 896, 1792, jb2x, jb2y, c, g, lab1, ceJ);
        if (c == 0){
            const int rowbase = wrow0 + 64 + g * 4;
            const int4  m4 = *(const int4*)(mask + rowbase);
            const float4 e4 = *(const float4*)(ws + (rowbase & 63));
            const float4 s4 = *(const float4*)(ws + 64 + (rowbase & 63));
            const int   mm[4] = {m4.x, m4.y, m4.z, m4.w};
            const float ee[4] = {e4.x, e4.y, e4.z, e4.w};
            const float sv[4] = {s4.x, s4.y, s4.z, s4.w};
            float rw[4], mcv[4], mjv[4];
#pragma unroll
            for (int rr = 0; rr < 4; rr++){
                float mf = mm[rr] ? 1.f : 0.f;
                float cec = ceC1[rr], cej = ceJ[rr];
                rw[rr]  = mf * sv[rr] * (ee[rr] - cec - 0.5f * fmaxf(cec - cej, 0.f));
                mcv[rr] = mf * cec;  mjv[rr] = mf * cej;
            }
            *(float4*)(out + rowbase)              = (float4){rw[0], rw[1], rw[2], rw[3]};
            *(float4*)(ws + 512 + rowbase)         = (float4){mcv[0], mcv[1], mcv[2], mcv[3]};
            *(float4*)(ws + 512 + NROWS + rowbase) = (float4){mjv[0], mjv[1], mjv[2], mjv[3]};
        }
    }
}

// ======================= aux reductions ====================================
__global__ void k_aux1(float* __restrict__ ws){
    int t = blockIdx.x, tid = threadIdx.x;
    const float* mc = ws + 512;
    const float* mj = ws + 512 + NROWS;
    float sc = 0.f, sj = 0.f;
    for (int b = tid; b < B_; b += 256){ sc += mc[b * T_ + t]; sj += mj[b * T_ + t]; }
    for (int m = 1; m < 64; m <<= 1){ sc += __shfl_xor(sc, m); sj += __shfl_xor(sj, m); }
    __shared__ float sh[8];
    int w = tid >> 6, l = tid & 63;
    if (l == 0){ sh[w] = sc; sh[4 + w] = sj; }
    __syncthreads();
    if (tid == 0){
        float a0 = sh[0] + sh[1] + sh[2] + sh[3];
        float a1 = sh[4] + sh[5] + sh[6] + sh[7];
        ws[192 + t] = ws[64 + t] * 0.5f * (a0 + a1) / fmaxf(ws[128 + t], 1.f);
    }
}

__global__ void k_aux2(const float* __restrict__ ws, float* __restrict__ out){
    int l = threadIdx.x;
    float cv = ws[192 + l], sv = ws[64 + l];
    for (int m = 1; m < 64; m <<= 1){ cv += __shfl_xor(cv, m); sv += __shfl_xor(sv, m); }
    if (l == 0) out[NROWS] = (sv > 0.f) ? cv / fmaxf(sv, 1.f) : 0.f;
}

extern "C" void kernel_launch(void* const* d_in, const int* in_sizes, int n_in,
                              void* d_out, int out_size, void* d_ws, size_t ws_size,
                              hipStream_t stream) {
    const float* xc     = (const float*)d_in[0];
    const float* xs     = (const float*)d_in[1];
    const int*   labels = (const int*)d_in[2];
    const int*   mask   = (const int*)d_in[3];
    const float* ce_w1  = (const float*)d_in[4];
    const float* ce_b1  = (const float*)d_in[5];
    const float* ce_w2  = (const float*)d_in[6];
    const float* ce_b2  = (const float*)d_in[7];
    const float* se_w1  = (const float*)d_in[8];
    const float* se_b1  = (const float*)d_in[9];
    const float* se_w2  = (const float*)d_in[10];
    const float* se_b2  = (const float*)d_in[11];
    const float* cd_g   = (const float*)d_in[12];
    const float* cd_b   = (const float*)d_in[13];
    const float* cd_w1  = (const float*)d_in[14];
    const float* cd_b1  = (const float*)d_in[15];
    const float* cd_w2  = (const float*)d_in[16];
    const float* cd_b2  = (const float*)d_in[17];
    const float* jd_g   = (const float*)d_in[18];
    const float* jd_b   = (const float*)d_in[19];
    const float* jd_w1  = (const float*)d_in[20];
    const float* jd_b1  = (const float*)d_in[21];
    const float* jd_w2  = (const float*)d_in[22];
    const float* jd_b2  = (const float*)d_in[23];
    float* ws  = (float*)d_ws;
    float* out = (float*)d_out;

    k_prep<<<513, 256, 0, stream>>>(ce_w1, ce_w2, se_w1, se_w2, cd_w1, jd_w1,
                                    ce_b1, ce_b2, se_b1, se_b2, cd_g, cd_b,
                                    cd_b1, jd_g, jd_b, jd_b1, cd_w2, jd_w2,
                                    mask, labels, ws);
    k_main<<<2048, 256, 0, stream>>>(xc, xs, labels, mask, cd_b2, jd_b2, ws, out);
    k_aux1<<<64, 256, 0, stream>>>(ws);
    k_aux2<<<1, 64, 0, stream>>>(ws, out);
}

// Round 10
// 308.054 us; speedup vs baseline: 4.1283x; 4.1283x over previous
//
#include <hip/hip_runtime.h>
#include <hip/hip_fp16.h>

#define B_ 4096
#define T_ 64
#define NROWS (B_*T_)      // 262144
#define BLOB_B 2099200     // byte offset of weight blob in ws
#define JD_REL 163840      // jd_w1 K=256 image offset WITHIN blob (64 KB)
#define PIMG_B (BLOB_B + 229376)      // param image (4 KB f16), absolute in ws

typedef _Float16 f16x8 __attribute__((ext_vector_type(8)));
typedef float    f32x4 __attribute__((ext_vector_type(4)));

__device__ __forceinline__ float gelu_f(float x){
    return 0.5f * x * (1.0f + erff(x * 0.70710678118654752f));
}

// ---------- async global->LDS, 16B per lane, linear dest ----------
__device__ __forceinline__ void gll16(const void* g, void* l){
    __builtin_amdgcn_global_load_lds(
        (const __attribute__((address_space(1))) void*)g,
        (__attribute__((address_space(3))) void*)l, 16, 0, 0);
}

// stage 32KB image with 512 threads: 4 issues per lane (8KB per round)
__device__ __forceinline__ void stage32(const char* gsrc, char* dst, int wave, int lane){
#pragma unroll
    for (int r = 0; r < 4; r++){
        const int off = r * 8192 + wave * 1024;
        gll16(gsrc + off + lane * 16, dst + off);
    }
}

// stage 4KB param image: waves 0..3 only
__device__ __forceinline__ void stage_p(const char* gsrc, char* dst, int wave, int lane){
    if (wave < 4) gll16(gsrc + wave * 1024 + lane * 16, dst + wave * 1024);
}

// ---------- input rows -> f16 A-fragments (K=128 -> 4 frags)
__device__ __forceinline__ void load_in(f16x8* a, const float* __restrict__ p, int g){
#pragma unroll
    for (int ks = 0; ks < 4; ks++){
        const float* q = p + ks * 32 + g * 8;
        float4 v0 = *(const float4*)q, v1 = *(const float4*)(q + 4);
        f16x8 t;
        t[0]=(_Float16)v0.x; t[1]=(_Float16)v0.y; t[2]=(_Float16)v0.z; t[3]=(_Float16)v0.w;
        t[4]=(_Float16)v1.x; t[5]=(_Float16)v1.y; t[6]=(_Float16)v1.z; t[7]=(_Float16)v1.w;
        a[ks] = t;
    }
}

// ---------- A-fragments from wave-private ab tile [16][128] f16
__device__ __forceinline__ void load_a(f16x8* a, const char* ab, int c, int g){
    const int rswz = (c & 7) << 4;
    const char* rp = ab + c * 256;
#pragma unroll
    for (int ks = 0; ks < 4; ks++)
        a[ks] = *(const f16x8*)(rp + ((ks * 64 + g * 16) ^ rswz));
}

// ---------- 8-tile MFMA, K=128, row stride 256B
__device__ __forceinline__ void mfma_tile(f32x4* acc, const f16x8* a,
                                          const char* wb, int c, int g){
#pragma unroll
    for (int n = 0; n < 8; n++){
        const int r = n * 16 + c;
        const char* rp = wb + r * 256;
        const int swz = (r & 7) << 4;
#pragma unroll
        for (int ks = 0; ks < 4; ks++){
            f16x8 b = *(const f16x8*)(rp + ((ks * 64 + g * 16) ^ swz));
            acc[n] = __builtin_amdgcn_mfma_f32_16x16x32_f16(a[ks], b, acc[n], 0, 0, 0);
        }
    }
}

// ---------- 8-tile MFMA, K=256, row stride 512B (joint decoder)
__device__ __forceinline__ void mfma_tile8(f32x4* acc, const f16x8* a,
                                           const char* wb, int c, int g){
#pragma unroll
    for (int n = 0; n < 8; n++){
        const int r = n * 16 + c;
        const char* rp = wb + r * 512;
        const int swz = (r & 7) << 4;
#pragma unroll
        for (int ks = 0; ks < 8; ks++){
            f16x8 b = *(const f16x8*)(rp + ((ks * 64 + g * 16) ^ swz));
            acc[n] = __builtin_amdgcn_mfma_f32_16x16x32_f16(a[ks], b, acc[n], 0, 0, 0);
        }
    }
}

// ---------- LN'd A-fragments in registers
__device__ __forceinline__ void build_y(f16x8* y, const f16x8* x, float mu, float rs,
                                        const char* sp, int goff, int boff, int g){
#pragma unroll
    for (int ks = 0; ks < 4; ks++){
        f16x8 gam = *(const f16x8*)(sp + goff * 2 + ks * 64 + g * 16);
        f16x8 bet = *(const f16x8*)(sp + boff * 2 + ks * 64 + g * 16);
        f16x8 t;
#pragma unroll
        for (int j = 0; j < 8; j++){
            float v = ((float)x[ks][j] - mu) * rs * (float)gam[j] + (float)bet[j];
            t[j] = (_Float16)v;
        }
        y[ks] = t;
    }
}

// ---------- per-row stats over lane's 32 elems + 4-lane-group reduce
__device__ __forceinline__ void row_stats(const f16x8* x, float& s0, float& s1){
    s0 = 0.f; s1 = 0.f;
#pragma unroll
    for (int ks = 0; ks < 4; ks++)
#pragma unroll
        for (int j = 0; j < 8; j++){ float v = (float)x[ks][j]; s0 += v; s1 += v*v; }
    s0 += __shfl_xor(s0, 16); s0 += __shfl_xor(s0, 32);
    s1 += __shfl_xor(s1, 16); s1 += __shfl_xor(s1, 32);
}

// ---------- logits + CE from C-layout acc (shfl-dot over 16 c-lanes)
__device__ __forceinline__ void logits_ce(const f32x4* acc, const char* sp,
                                          int b1off, int w2off, float b2x, float b2y,
                                          int c, int g, int lab, float* ce){
    const _Float16* sbf = (const _Float16*)sp;
    float l0[4] = {0,0,0,0}, l1[4] = {0,0,0,0};
#pragma unroll
    for (int n = 0; n < 8; n++){
        const int r = n * 16 + c;
        float b1v = (float)sbf[b1off + r];
        float wx  = (float)sbf[w2off + 2 * r];
        float wy  = (float)sbf[w2off + 2 * r + 1];
#pragma unroll
        for (int rr = 0; rr < 4; rr++){
            float hv = gelu_f(acc[n][rr] + b1v);
            l0[rr] += hv * wx; l1[rr] += hv * wy;
        }
    }
#pragma unroll
    for (int rr = 0; rr < 4; rr++){
#pragma unroll
        for (int m = 1; m < 16; m <<= 1){ l0[rr] += __shfl_xor(l0[rr], m); l1[rr] += __shfl_xor(l1[rr], m); }
        float v0 = l0[rr] + b2x, v1 = l1[rr] + b2y;
        float mx = fmaxf(v0, v1);
        float lse = mx + logf(expf(v0 - mx) + expf(v1 - mx));
        ce[rr] = lse - (lab ? v1 : v0);
    }
}

// ---------- MFMA phase with bias(+gelu) epilogue into ab tile
template<bool GELU>
__device__ __forceinline__ void phase_store(const f16x8* a, const char* wb, char* ab,
                                            const char* sp, int boff, int c, int g){
    const _Float16* sbf = (const _Float16*)sp;
    f32x4 acc[8];
#pragma unroll
    for (int n = 0; n < 8; n++) acc[n] = (f32x4){0.f,0.f,0.f,0.f};
    mfma_tile(acc, a, wb, c, g);
#pragma unroll
    for (int n = 0; n < 8; n++){
        const int col = n * 16 + c;
        float bi = (float)sbf[boff + col];
#pragma unroll
        for (int rr = 0; rr < 4; rr++){
            float v = acc[n][rr] + bi;
            if (GELU) v = gelu_f(v);
            int row = g * 4 + rr;
            *(_Float16*)(ab + row * 256 + ((col << 1) ^ ((row & 7) << 4))) = (_Float16)v;
        }
    }
}

// ======================= prep + stats (merged) =============================
__global__ void k_prep(const float* __restrict__ ce_w1, const float* __restrict__ ce_w2,
                       const float* __restrict__ se_w1, const float* __restrict__ se_w2,
                       const float* __restrict__ cd_w1, const float* __restrict__ jd_w1,
                       const float* __restrict__ ce_b1, const float* __restrict__ ce_b2,
                       const float* __restrict__ se_b1, const float* __restrict__ se_b2,
                       const float* __restrict__ cd_g,  const float* __restrict__ cd_bt,
                       const float* __restrict__ cd_b1, const float* __restrict__ jd_g,
                       const float* __restrict__ jd_bt, const float* __restrict__ jd_b1,
                       const float* __restrict__ cd_w2, const float* __restrict__ jd_w2,
                       const int* __restrict__ mask, const int* __restrict__ labels,
                       float* __restrict__ ws){
    char* blob = (char*)ws + BLOB_B;
    const int bid = blockIdx.x, tid = threadIdx.x;
    if (bid < 320){
        // 5 K=128 matrices: ce_w1, ce_w2, se_w1, se_w2, cd_w1
        int e = bid * 256 + tid;
        int m = e >> 14, idx = e & 16383;
        int k = idx >> 7, cc = idx & 127;
        const float* src;
        switch (m){
            case 0: src = ce_w1; break;
            case 1: src = ce_w2; break;
            case 2: src = se_w1; break;
            case 3: src = se_w2; break;
            default: src = cd_w1; break;
        }
        float v = src[k * 128 + cc];
        int byte = m * 32768 + cc * 256 + ((k << 1) ^ ((cc & 7) << 4));
        *(_Float16*)(blob + byte) = (_Float16)v;
    } else if (bid < 448){
        // jd_w1 as single K=256 image, row stride 512B, at blob+JD_REL
        int e = (bid - 320) * 256 + tid;
        int k = e >> 7, cc = e & 127;
        float v = jd_w1[k * 128 + cc];
        int byte = JD_REL + cc * 512 + ((k << 1) ^ ((cc & 7) << 4));
        *(_Float16*)(blob + byte) = (_Float16)v;
    } else if (bid < 512){
        // stats for t = bid-448
        int t = bid - 448;
        float c0 = 0.f, c1 = 0.f;
        for (int b = tid; b < B_; b += 256){
            if (mask[b * T_ + t]){
                if (labels[b] == 1) c1 += 1.f; else c0 += 1.f;
            }
        }
        for (int m = 1; m < 64; m <<= 1){ c0 += __shfl_xor(c0, m); c1 += __shfl_xor(c1, m); }
        __shared__ float sh[8];
        int w = tid >> 6, l = tid & 63;
        if (l == 0){ sh[w] = c0; sh[4 + w] = c1; }
        __syncthreads();
        if (tid == 0){
            float a0 = sh[0] + sh[1] + sh[2] + sh[3];
            float a1 = sh[4] + sh[5] + sh[6] + sh[7];
            float tot = a0 + a1;
            float d = fmaxf(tot, 1.f);
            float p0 = a0 / d, p1 = a1 / d;
            float ent = -(p0 * logf(p0 + 1e-8f) + p1 * logf(p1 + 1e-8f));
            ws[t] = ent;
            ws[64 + t] = (tot >= 2.f) ? 1.f : 0.f;
            ws[128 + t] = tot;
        }
    } else {
        _Float16* p = (_Float16*)((char*)ws + PIMG_B);
        if (tid < 128){
            p[tid]       = (_Float16)ce_b1[tid]; p[128 + tid] = (_Float16)ce_b2[tid];
            p[256 + tid] = (_Float16)se_b1[tid]; p[384 + tid] = (_Float16)se_b2[tid];
            p[512 + tid] = (_Float16)cd_g[tid];  p[640 + tid] = (_Float16)cd_bt[tid];
            p[768 + tid] = (_Float16)cd_b1[tid]; p[896 + tid] = (_Float16)jd_b1[tid];
        } else {
            int i = tid - 128;
            p[1024 + i] = (_Float16)jd_g[i];        p[1152 + i] = (_Float16)jd_g[128 + i];
            p[1280 + i] = (_Float16)jd_bt[i];       p[1408 + i] = (_Float16)jd_bt[128 + i];
            p[1536 + 2*i] = (_Float16)cd_w2[2*i];   p[1537 + 2*i] = (_Float16)cd_w2[2*i+1];
            p[1792 + 2*i] = (_Float16)jd_w2[2*i];   p[1793 + 2*i] = (_Float16)jd_w2[2*i+1];
        }
    }
}

// ======================= main fused kernel =================================
// 512 threads (8 waves x 16 rows = 128 rows/block), grid 2048.
// LDS 69632: [0,32K)=wbuf | [32K,64K)=8 wave ab tiles | [64K,68K)=params.
// Joint phase reads [0,64K) as a single K=256 jd_w1 image.
// Per-wave state is R7-sized (one chunk per wave) -> no spill.
__global__ __launch_bounds__(512, 2) void k_main(
    const float* __restrict__ xc, const float* __restrict__ xs,
    const int* __restrict__ labels, const int* __restrict__ mask,
    const float* __restrict__ cd_b2, const float* __restrict__ jd_b2,
    float* __restrict__ ws, float* __restrict__ out)
{
    __shared__ __align__(16) char lds[69632];

    const int tid = threadIdx.x;
    const int wave = tid >> 6, lane = tid & 63;
    const int c = lane & 15, g = lane >> 4;
    const int wrow0 = blockIdx.x * 128 + wave * 16;
    char* const ab = lds + 32768 + wave * 4096;
    const char* sp = lds + 65536;
    const char* blob = (const char*)ws + BLOB_B;
    const int lab = labels[wrow0 >> 6];
    const float cb2x = cd_b2[0], cb2y = cd_b2[1];
    const float jb2x = jd_b2[0], jb2y = jd_b2[1];

    f16x8 fr[4], cr[4], sr[4];
    float ceC[4], ceJ[4];
    float s0c, s1c, mcv, rcv, jmv, jrv;

    // ---- P0: stage params + ce_w1; prefetch xc ----------------------------
    stage_p((const char*)ws + PIMG_B, lds + 65536, wave, lane);
    stage32(blob + 0 * 32768, lds, wave, lane);
    load_in(fr, xc + (wrow0 + c) * 128, g);
    __syncthreads();                                            // B1: ce_w1 ready

    // ---- P1: enc1 causal ---------------------------------------------------
    phase_store<true>(fr, lds, ab, sp, 0, c, g);
    __syncthreads();                                            // B2: ce_w1 retired
    stage32(blob + 1 * 32768, lds, wave, lane);                 // ce_w2
    load_a(fr, ab, c, g);                                       // filler
    __syncthreads();                                            // B3: ce_w2 ready

    // ---- P2: enc2 causal -> c_rep tile ------------------------------------
    phase_store<false>(fr, lds, ab, sp, 128, c, g);
    __syncthreads();                                            // B4: ce_w2 retired
    stage32(blob + 2 * 32768, lds, wave, lane);                 // se_w1
    load_in(fr, xs + (wrow0 + c) * 128, g);                     // xs load (overlapped)
    load_a(cr, ab, c, g);  row_stats(cr, s0c, s1c);             // fillers
    __syncthreads();                                            // B5: se_w1 ready

    // ---- P3: enc1 spurious -------------------------------------------------
    phase_store<true>(fr, lds, ab, sp, 256, c, g);
    __syncthreads();                                            // B6: se_w1 retired
    stage32(blob + 3 * 32768, lds, wave, lane);                 // se_w2
    load_a(fr, ab, c, g);                                       // filler
    __syncthreads();                                            // B7: se_w2 ready

    // ---- P4: enc2 spurious -> s_rep tile; all stats ------------------------
    phase_store<false>(fr, lds, ab, sp, 384, c, g);
    __syncthreads();                                            // B8: se_w2 retired
    stage32(blob + 4 * 32768, lds, wave, lane);                 // cd_w1
    {
        float s0s, s1s;
        load_a(sr, ab, c, g); row_stats(sr, s0s, s1s);
        mcv = s0c * (1.f/128.f);
        rcv = rsqrtf(s1c * (1.f/128.f) - mcv * mcv + 1e-5f);
        jmv = (s0c + s0s) * (1.f/256.f);
        jrv = rsqrtf((s1c + s1s) * (1.f/256.f) - jmv * jmv + 1e-5f);
    }
    __syncthreads();                                            // B9: cd_w1 ready; ab reads done
    stage32(blob + JD_REL + 32768, lds + 32768, wave, lane);    // jd rows 64..127 -> ab region

    // ---- P5: causal decoder (in-reg) + ceC ---------------------------------
    {
        f32x4 acc[8];
        build_y(fr, cr, mcv, rcv, sp, 512, 640, g);
#pragma unroll
        for (int n = 0; n < 8; n++) acc[n] = (f32x4){0.f,0.f,0.f,0.f};
        mfma_tile(acc, fr, lds, c, g);
        logits_ce(acc, sp, 768, 1536, cb2x, cb2y, c, g, lab, ceC);
    }
    __syncthreads();                                            // B10: cd_w1 retired; jd-upper landed
    stage32(blob + JD_REL, lds, wave, lane);                    // jd rows 0..63 -> wbuf
    f16x8 a8[8];
    build_y(&a8[0], cr, jmv, jrv, sp, 1024, 1280, g);           // fillers under gll
    build_y(&a8[4], sr, jmv, jrv, sp, 1152, 1408, g);
    __syncthreads();                                            // B11: full jd image ready

    // ---- P6: joint decoder (K=256) + epilogue ------------------------------
    {
        const int rowbase = wrow0 + g * 4;
        const int4  m4 = *(const int4*)(mask + rowbase);
        const float4 e4 = *(const float4*)(ws + (rowbase & 63));
        const float4 s4 = *(const float4*)(ws + 64 + (rowbase & 63));

        f32x4 acc[8];
#pragma unroll
        for (int n = 0; n < 8; n++) acc[n] = (f32x4){0.f,0.f,0.f,0.f};
        mfma_tile8(acc, a8, lds, c, g);
        logits_ce(acc, sp, 896, 1792, jb2x, jb2y, c, g, lab, ceJ);

        if (c == 0){
            const int   mm[4] = {m4.x, m4.y, m4.z, m4.w};
            const float ee[4] = {e4.x, e4.y, e4.z, e4.w};
            const float sv[4] = {s4.x, s4.y, s4.z, s4.w};
            float rw[4], mcw[4], mjw[4];
#pragma unroll
            for (int rr = 0; rr < 4; rr++){
                float mf = mm[rr] ? 1.f : 0.f;
                float cec = ceC[rr], cej = ceJ[rr];
                rw[rr]  = mf * sv[rr] * (ee[rr] - cec - 0.5f * fmaxf(cec - cej, 0.f));
                mcw[rr] = mf * cec;  mjw[rr] = mf * cej;
            }
            *(float4*)(out + rowbase)              = (float4){rw[0], rw[1], rw[2], rw[3]};
            *(float4*)(ws + 512 + rowbase)         = (float4){mcw[0], mcw[1], mcw[2], mcw[3]};
            *(float4*)(ws + 512 + NROWS + rowbase) = (float4){mjw[0], mjw[1], mjw[2], mjw[3]};
        }
    }
}

// ======================= aux reductions ====================================
__global__ void k_aux1(float* __restrict__ ws){
    int t = blockIdx.x, tid = threadIdx.x;
    const float* mc = ws + 512;
    const float* mj = ws + 512 + NROWS;
    float sc = 0.f, sj = 0.f;
    for (int b = tid; b < B_; b += 256){ sc += mc[b * T_ + t]; sj += mj[b * T_ + t]; }
    for (int m = 1; m < 64; m <<= 1){ sc += __shfl_xor(sc, m); sj += __shfl_xor(sj, m); }
    __shared__ float sh[8];
    int w = tid >> 6, l = tid & 63;
    if (l == 0){ sh[w] = sc; sh[4 + w] = sj; }
    __syncthreads();
    if (tid == 0){
        float a0 = sh[0] + sh[1] + sh[2] + sh[3];
        float a1 = sh[4] + sh[5] + sh[6] + sh[7];
        ws[192 + t] = ws[64 + t] * 0.5f * (a0 + a1) / fmaxf(ws[128 + t], 1.f);
    }
}

__global__ void k_aux2(const float* __restrict__ ws, float* __restrict__ out){
    int l = threadIdx.x;
    float cv = ws[192 + l], sv = ws[64 + l];
    for (int m = 1; m < 64; m <<= 1){ cv += __shfl_xor(cv, m); sv += __shfl_xor(sv, m); }
    if (l == 0) out[NROWS] = (sv > 0.f) ? cv / fmaxf(sv, 1.f) : 0.f;
}

extern "C" void kernel_launch(void* const* d_in, const int* in_sizes, int n_in,
                              void* d_out, int out_size, void* d_ws, size_t ws_size,
                              hipStream_t stream) {
    const float* xc     = (const float*)d_in[0];
    const float* xs     = (const float*)d_in[1];
    const int*   labels = (const int*)d_in[2];
    const int*   mask   = (const int*)d_in[3];
    const float* ce_w1  = (const float*)d_in[4];
    const float* ce_b1  = (const float*)d_in[5];
    const float* ce_w2  = (const float*)d_in[6];
    const float* ce_b2  = (const float*)d_in[7];
    const float* se_w1  = (const float*)d_in[8];
    const float* se_b1  = (const float*)d_in[9];
    const float* se_w2  = (const float*)d_in[10];
    const float* se_b2  = (const float*)d_in[11];
    const float* cd_g   = (const float*)d_in[12];
    const float* cd_b   = (const float*)d_in[13];
    const float* cd_w1  = (const float*)d_in[14];
    const float* cd_b1  = (const float*)d_in[15];
    const float* cd_w2  = (const float*)d_in[16];
    const float* cd_b2  = (const float*)d_in[17];
    const float* jd_g   = (const float*)d_in[18];
    const float* jd_b   = (const float*)d_in[19];
    const float* jd_w1  = (const float*)d_in[20];
    const float* jd_b1  = (const float*)d_in[21];
    const float* jd_w2  = (const float*)d_in[22];
    const float* jd_b2  = (const float*)d_in[23];
    float* ws  = (float*)d_ws;
    float* out = (float*)d_out;

    k_prep<<<513, 256, 0, stream>>>(ce_w1, ce_w2, se_w1, se_w2, cd_w1, jd_w1,
                                    ce_b1, ce_b2, se_b1, se_b2, cd_g, cd_b,
                                    cd_b1, jd_g, jd_b, jd_b1, cd_w2, jd_w2,
                                    mask, labels, ws);
    k_main<<<2048, 512, 0, stream>>>(xc, xs, labels, mask, cd_b2, jd_b2, ws, out);
    k_aux1<<<64, 256, 0, stream>>>(ws);
    k_aux2<<<1, 64, 0, stream>>>(ws, out);
}

// Round 11
// 305.184 us; speedup vs baseline: 4.1671x; 1.0094x over previous
//
#include <hip/hip_runtime.h>
#include <hip/hip_fp16.h>

#define B_ 4096
#define T_ 64
#define NROWS (B_*T_)      // 262144
#define BLOB_B 2099200     // byte offset of weight blob in ws
#define JD_REL 163840      // jd_w1 K=256 image offset WITHIN blob (64 KB)
#define PIMG_B (BLOB_B + 229376)      // param image (4 KB f16), absolute in ws

typedef _Float16 f16x8 __attribute__((ext_vector_type(8)));
typedef float    f32x4 __attribute__((ext_vector_type(4)));

__device__ __forceinline__ float gelu_f(float x){
    return 0.5f * x * (1.0f + erff(x * 0.70710678118654752f));
}

// ---------- async global->LDS, 16B per lane, linear dest ----------
__device__ __forceinline__ void gll16(const void* g, void* l){
    __builtin_amdgcn_global_load_lds(
        (const __attribute__((address_space(1))) void*)g,
        (__attribute__((address_space(3))) void*)l, 16, 0, 0);
}

// stage 32KB image with 512 threads: 4 issues per lane (8KB per round)
__device__ __forceinline__ void stage32(const char* gsrc, char* dst, int wave, int lane){
#pragma unroll
    for (int r = 0; r < 4; r++){
        const int off = r * 8192 + wave * 1024;
        gll16(gsrc + off + lane * 16, dst + off);
    }
}

// stage 4KB param image: waves 0..3 only
__device__ __forceinline__ void stage_p(const char* gsrc, char* dst, int wave, int lane){
    if (wave < 4) gll16(gsrc + wave * 1024 + lane * 16, dst + wave * 1024);
}

// ---------- input rows -> f16 A-fragments (K=128 -> 4 frags)
__device__ __forceinline__ void load_in(f16x8* a, const float* __restrict__ p, int g){
#pragma unroll
    for (int ks = 0; ks < 4; ks++){
        const float* q = p + ks * 32 + g * 8;
        float4 v0 = *(const float4*)q, v1 = *(const float4*)(q + 4);
        f16x8 t;
        t[0]=(_Float16)v0.x; t[1]=(_Float16)v0.y; t[2]=(_Float16)v0.z; t[3]=(_Float16)v0.w;
        t[4]=(_Float16)v1.x; t[5]=(_Float16)v1.y; t[6]=(_Float16)v1.z; t[7]=(_Float16)v1.w;
        a[ks] = t;
    }
}

// ---------- A-fragments from wave-private ab tile [16][128] f16
__device__ __forceinline__ void load_a(f16x8* a, const char* ab, int c, int g){
    const int rswz = (c & 7) << 4;
    const char* rp = ab + c * 256;
#pragma unroll
    for (int ks = 0; ks < 4; ks++)
        a[ks] = *(const f16x8*)(rp + ((ks * 64 + g * 16) ^ rswz));
}

// ---------- 8-tile MFMA, K=128, row stride 256B
__device__ __forceinline__ void mfma_tile(f32x4* acc, const f16x8* a,
                                          const char* wb, int c, int g){
#pragma unroll
    for (int n = 0; n < 8; n++){
        const int r = n * 16 + c;
        const char* rp = wb + r * 256;
        const int swz = (r & 7) << 4;
#pragma unroll
        for (int ks = 0; ks < 4; ks++){
            f16x8 b = *(const f16x8*)(rp + ((ks * 64 + g * 16) ^ swz));
            acc[n] = __builtin_amdgcn_mfma_f32_16x16x32_f16(a[ks], b, acc[n], 0, 0, 0);
        }
    }
}

// ---------- 8-tile MFMA half of K=256 (row stride 512B), koff = 0 or 256 bytes
__device__ __forceinline__ void mfma_tile8h(f32x4* acc, const f16x8* a,
                                            const char* wb, int c, int g, int koff){
#pragma unroll
    for (int n = 0; n < 8; n++){
        const int r = n * 16 + c;
        const char* rp = wb + r * 512 + koff;   // swz<128 so XOR stays within half
        const int swz = (r & 7) << 4;
#pragma unroll
        for (int ks = 0; ks < 4; ks++){
            f16x8 b = *(const f16x8*)(rp + ((ks * 64 + g * 16) ^ swz));
            acc[n] = __builtin_amdgcn_mfma_f32_16x16x32_f16(a[ks], b, acc[n], 0, 0, 0);
        }
    }
}

// ---------- LN'd A-fragments in registers
__device__ __forceinline__ void build_y(f16x8* y, const f16x8* x, float mu, float rs,
                                        const char* sp, int goff, int boff, int g){
#pragma unroll
    for (int ks = 0; ks < 4; ks++){
        f16x8 gam = *(const f16x8*)(sp + goff * 2 + ks * 64 + g * 16);
        f16x8 bet = *(const f16x8*)(sp + boff * 2 + ks * 64 + g * 16);
        f16x8 t;
#pragma unroll
        for (int j = 0; j < 8; j++){
            float v = ((float)x[ks][j] - mu) * rs * (float)gam[j] + (float)bet[j];
            t[j] = (_Float16)v;
        }
        y[ks] = t;
    }
}

// ---------- per-row stats over lane's 32 elems + 4-lane-group reduce
__device__ __forceinline__ void row_stats(const f16x8* x, float& s0, float& s1){
    s0 = 0.f; s1 = 0.f;
#pragma unroll
    for (int ks = 0; ks < 4; ks++)
#pragma unroll
        for (int j = 0; j < 8; j++){ float v = (float)x[ks][j]; s0 += v; s1 += v*v; }
    s0 += __shfl_xor(s0, 16); s0 += __shfl_xor(s0, 32);
    s1 += __shfl_xor(s1, 16); s1 += __shfl_xor(s1, 32);
}

// ---------- logits + CE from C-layout acc (shfl-dot over 16 c-lanes)
__device__ __forceinline__ void logits_ce(const f32x4* acc, const char* sp,
                                          int b1off, int w2off, float b2x, float b2y,
                                          int c, int g, int lab, float* ce){
    const _Float16* sbf = (const _Float16*)sp;
    float l0[4] = {0,0,0,0}, l1[4] = {0,0,0,0};
#pragma unroll
    for (int n = 0; n < 8; n++){
        const int r = n * 16 + c;
        float b1v = (float)sbf[b1off + r];
        float wx  = (float)sbf[w2off + 2 * r];
        float wy  = (float)sbf[w2off + 2 * r + 1];
#pragma unroll
        for (int rr = 0; rr < 4; rr++){
            float hv = gelu_f(acc[n][rr] + b1v);
            l0[rr] += hv * wx; l1[rr] += hv * wy;
        }
    }
#pragma unroll
    for (int rr = 0; rr < 4; rr++){
#pragma unroll
        for (int m = 1; m < 16; m <<= 1){ l0[rr] += __shfl_xor(l0[rr], m); l1[rr] += __shfl_xor(l1[rr], m); }
        float v0 = l0[rr] + b2x, v1 = l1[rr] + b2y;
        float mx = fmaxf(v0, v1);
        float lse = mx + logf(expf(v0 - mx) + expf(v1 - mx));
        ce[rr] = lse - (lab ? v1 : v0);
    }
}

// ---------- MFMA phase with bias(+gelu) epilogue into ab tile
template<bool GELU>
__device__ __forceinline__ void phase_store(const f16x8* a, const char* wb, char* ab,
                                            const char* sp, int boff, int c, int g){
    const _Float16* sbf = (const _Float16*)sp;
    f32x4 acc[8];
#pragma unroll
    for (int n = 0; n < 8; n++) acc[n] = (f32x4){0.f,0.f,0.f,0.f};
    mfma_tile(acc, a, wb, c, g);
#pragma unroll
    for (int n = 0; n < 8; n++){
        const int col = n * 16 + c;
        float bi = (float)sbf[boff + col];
#pragma unroll
        for (int rr = 0; rr < 4; rr++){
            float v = acc[n][rr] + bi;
            if (GELU) v = gelu_f(v);
            int row = g * 4 + rr;
            *(_Float16*)(ab + row * 256 + ((col << 1) ^ ((row & 7) << 4))) = (_Float16)v;
        }
    }
}

// ======================= prep + stats (merged) =============================
__global__ void k_prep(const float* __restrict__ ce_w1, const float* __restrict__ ce_w2,
                       const float* __restrict__ se_w1, const float* __restrict__ se_w2,
                       const float* __restrict__ cd_w1, const float* __restrict__ jd_w1,
                       const float* __restrict__ ce_b1, const float* __restrict__ ce_b2,
                       const float* __restrict__ se_b1, const float* __restrict__ se_b2,
                       const float* __restrict__ cd_g,  const float* __restrict__ cd_bt,
                       const float* __restrict__ cd_b1, const float* __restrict__ jd_g,
                       const float* __restrict__ jd_bt, const float* __restrict__ jd_b1,
                       const float* __restrict__ cd_w2, const float* __restrict__ jd_w2,
                       const int* __restrict__ mask, const int* __restrict__ labels,
                       float* __restrict__ ws){
    char* blob = (char*)ws + BLOB_B;
    const int bid = blockIdx.x, tid = threadIdx.x;
    if (bid < 320){
        int e = bid * 256 + tid;
        int m = e >> 14, idx = e & 16383;
        int k = idx >> 7, cc = idx & 127;
        const float* src;
        switch (m){
            case 0: src = ce_w1; break;
            case 1: src = ce_w2; break;
            case 2: src = se_w1; break;
            case 3: src = se_w2; break;
            default: src = cd_w1; break;
        }
        float v = src[k * 128 + cc];
        int byte = m * 32768 + cc * 256 + ((k << 1) ^ ((cc & 7) << 4));
        *(_Float16*)(blob + byte) = (_Float16)v;
    } else if (bid < 448){
        int e = (bid - 320) * 256 + tid;
        int k = e >> 7, cc = e & 127;
        float v = jd_w1[k * 128 + cc];
        int byte = JD_REL + cc * 512 + ((k << 1) ^ ((cc & 7) << 4));
        *(_Float16*)(blob + byte) = (_Float16)v;
    } else if (bid < 512){
        int t = bid - 448;
        float c0 = 0.f, c1 = 0.f;
        for (int b = tid; b < B_; b += 256){
            if (mask[b * T_ + t]){
                if (labels[b] == 1) c1 += 1.f; else c0 += 1.f;
            }
        }
        for (int m = 1; m < 64; m <<= 1){ c0 += __shfl_xor(c0, m); c1 += __shfl_xor(c1, m); }
        __shared__ float sh[8];
        int w = tid >> 6, l = tid & 63;
        if (l == 0){ sh[w] = c0; sh[4 + w] = c1; }
        __syncthreads();
        if (tid == 0){
            float a0 = sh[0] + sh[1] + sh[2] + sh[3];
            float a1 = sh[4] + sh[5] + sh[6] + sh[7];
            float tot = a0 + a1;
            float d = fmaxf(tot, 1.f);
            float p0 = a0 / d, p1 = a1 / d;
            float ent = -(p0 * logf(p0 + 1e-8f) + p1 * logf(p1 + 1e-8f));
            ws[t] = ent;
            ws[64 + t] = (tot >= 2.f) ? 1.f : 0.f;
            ws[128 + t] = tot;
        }
    } else {
        _Float16* p = (_Float16*)((char*)ws + PIMG_B);
        if (tid < 128){
            p[tid]       = (_Float16)ce_b1[tid]; p[128 + tid] = (_Float16)ce_b2[tid];
            p[256 + tid] = (_Float16)se_b1[tid]; p[384 + tid] = (_Float16)se_b2[tid];
            p[512 + tid] = (_Float16)cd_g[tid];  p[640 + tid] = (_Float16)cd_bt[tid];
            p[768 + tid] = (_Float16)cd_b1[tid]; p[896 + tid] = (_Float16)jd_b1[tid];
        } else {
            int i = tid - 128;
            p[1024 + i] = (_Float16)jd_g[i];        p[1152 + i] = (_Float16)jd_g[128 + i];
            p[1280 + i] = (_Float16)jd_bt[i];       p[1408 + i] = (_Float16)jd_bt[128 + i];
            p[1536 + 2*i] = (_Float16)cd_w2[2*i];   p[1537 + 2*i] = (_Float16)cd_w2[2*i+1];
            p[1792 + 2*i] = (_Float16)jd_w2[2*i];   p[1793 + 2*i] = (_Float16)jd_w2[2*i+1];
        }
    }
}

// ======================= main fused kernel =================================
// 512 threads (8 waves x 16 rows = 128 rows/block), grid 2048.
// LDS 69632: [0,32K)=wbuf | [32K,64K)=8 wave ab tiles | [64K,68K)=params.
// Register diet: no a8 (two-half joint MFMA reusing fr), epilogue inside c==0.
// Target: arch<=96 + 32 AGPR = 128 total -> 2 blocks/CU.
__global__ __launch_bounds__(512, 2) void k_main(
    const float* __restrict__ xc, const float* __restrict__ xs,
    const int* __restrict__ labels, const int* __restrict__ mask,
    const float* __restrict__ cd_b2, const float* __restrict__ jd_b2,
    float* __restrict__ ws, float* __restrict__ out)
{
    __shared__ __align__(16) char lds[69632];

    const int tid = threadIdx.x;
    const int wave = tid >> 6, lane = tid & 63;
    const int c = lane & 15, g = lane >> 4;
    const int wrow0 = blockIdx.x * 128 + wave * 16;
    char* const ab = lds + 32768 + wave * 4096;
    const char* sp = lds + 65536;
    const char* blob = (const char*)ws + BLOB_B;
    const int lab = labels[wrow0 >> 6];
    const float cb2x = cd_b2[0], cb2y = cd_b2[1];
    const float jb2x = jd_b2[0], jb2y = jd_b2[1];

    f16x8 fr[4], cr[4], sr[4];
    float ceC[4], ceJ[4];
    float s0c, s1c, mcv, rcv, jmv, jrv;

    // ---- P0: stage params + ce_w1; prefetch xc ----------------------------
    stage_p((const char*)ws + PIMG_B, lds + 65536, wave, lane);
    stage32(blob + 0 * 32768, lds, wave, lane);
    load_in(fr, xc + (wrow0 + c) * 128, g);
    __syncthreads();                                            // B1: ce_w1 ready

    // ---- P1: enc1 causal ---------------------------------------------------
    phase_store<true>(fr, lds, ab, sp, 0, c, g);
    __syncthreads();                                            // B2: ce_w1 retired
    stage32(blob + 1 * 32768, lds, wave, lane);                 // ce_w2
    load_a(fr, ab, c, g);                                       // filler
    __syncthreads();                                            // B3: ce_w2 ready

    // ---- P2: enc2 causal -> c_rep tile ------------------------------------
    phase_store<false>(fr, lds, ab, sp, 128, c, g);
    __syncthreads();                                            // B4: ce_w2 retired
    stage32(blob + 2 * 32768, lds, wave, lane);                 // se_w1
    load_in(fr, xs + (wrow0 + c) * 128, g);                     // xs load (overlapped)
    load_a(cr, ab, c, g);  row_stats(cr, s0c, s1c);             // fillers
    __syncthreads();                                            // B5: se_w1 ready

    // ---- P3: enc1 spurious -------------------------------------------------
    phase_store<true>(fr, lds, ab, sp, 256, c, g);
    __syncthreads();                                            // B6: se_w1 retired
    stage32(blob + 3 * 32768, lds, wave, lane);                 // se_w2
    load_a(fr, ab, c, g);                                       // filler
    __syncthreads();                                            // B7: se_w2 ready

    // ---- P4: enc2 spurious -> s_rep tile; all stats ------------------------
    phase_store<false>(fr, lds, ab, sp, 384, c, g);
    __syncthreads();                                            // B8: se_w2 retired
    stage32(blob + 4 * 32768, lds, wave, lane);                 // cd_w1
    {
        float s0s, s1s;
        load_a(sr, ab, c, g); row_stats(sr, s0s, s1s);
        mcv = s0c * (1.f/128.f);
        rcv = rsqrtf(s1c * (1.f/128.f) - mcv * mcv + 1e-5f);
        jmv = (s0c + s0s) * (1.f/256.f);
        jrv = rsqrtf((s1c + s1s) * (1.f/256.f) - jmv * jmv + 1e-5f);
    }
    __syncthreads();                                            // B9: cd_w1 ready; ab reads done
    stage32(blob + JD_REL + 32768, lds + 32768, wave, lane);    // jd cols 64..127 -> ab region

    // ---- P5: causal decoder (in-reg) + ceC ---------------------------------
    {
        f32x4 acc[8];
        build_y(fr, cr, mcv, rcv, sp, 512, 640, g);
#pragma unroll
        for (int n = 0; n < 8; n++) acc[n] = (f32x4){0.f,0.f,0.f,0.f};
        mfma_tile(acc, fr, lds, c, g);
        logits_ce(acc, sp, 768, 1536, cb2x, cb2y, c, g, lab, ceC);
    }
    __syncthreads();                                            // B10: cd_w1 retired; jd-upper landed
    stage32(blob + JD_REL, lds, wave, lane);                    // jd cols 0..63 -> wbuf
    build_y(fr, cr, jmv, jrv, sp, 1024, 1280, g);               // yjc frags (cr dies) under gll
    __syncthreads();                                            // B11: full jd image ready

    // ---- P6: joint decoder (K=256, two halves reusing fr) + epilogue -------
    {
        f32x4 acc[8];
#pragma unroll
        for (int n = 0; n < 8; n++) acc[n] = (f32x4){0.f,0.f,0.f,0.f};
        mfma_tile8h(acc, fr, lds, c, g, 0);                     // yjc @ jd k 0..127
        build_y(fr, sr, jmv, jrv, sp, 1152, 1408, g);           // yjs frags (sr dies)
        mfma_tile8h(acc, fr, lds, c, g, 256);                   // yjs @ jd k 128..255
        logits_ce(acc, sp, 896, 1792, jb2x, jb2y, c, g, lab, ceJ);
    }
    if (c == 0){
        const int rowbase = wrow0 + g * 4;
        const int4  m4 = *(const int4*)(mask + rowbase);
        const float4 e4 = *(const float4*)(ws + (rowbase & 63));
        const float4 s4 = *(const float4*)(ws + 64 + (rowbase & 63));
        const int   mm[4] = {m4.x, m4.y, m4.z, m4.w};
        const float ee[4] = {e4.x, e4.y, e4.z, e4.w};
        const float sv[4] = {s4.x, s4.y, s4.z, s4.w};
        float rw[4], mcw[4], mjw[4];
#pragma unroll
        for (int rr = 0; rr < 4; rr++){
            float mf = mm[rr] ? 1.f : 0.f;
            float cec = ceC[rr], cej = ceJ[rr];
            rw[rr]  = mf * sv[rr] * (ee[rr] - cec - 0.5f * fmaxf(cec - cej, 0.f));
            mcw[rr] = mf * cec;  mjw[rr] = mf * cej;
        }
        *(float4*)(out + rowbase)              = (float4){rw[0], rw[1], rw[2], rw[3]};
        *(float4*)(ws + 512 + rowbase)         = (float4){mcw[0], mcw[1], mcw[2], mcw[3]};
        *(float4*)(ws + 512 + NROWS + rowbase) = (float4){mjw[0], mjw[1], mjw[2], mjw[3]};
    }
}

// ======================= aux reductions ====================================
__global__ void k_aux1(float* __restrict__ ws){
    int t = blockIdx.x, tid = threadIdx.x;
    const float* mc = ws + 512;
    const float* mj = ws + 512 + NROWS;
    float sc = 0.f, sj = 0.f;
    for (int b = tid; b < B_; b += 256){ sc += mc[b * T_ + t]; sj += mj[b * T_ + t]; }
    for (int m = 1; m < 64; m <<= 1){ sc += __shfl_xor(sc, m); sj += __shfl_xor(sj, m); }
    __shared__ float sh[8];
    int w = tid >> 6, l = tid & 63;
    if (l == 0){ sh[w] = sc; sh[4 + w] = sj; }
    __syncthreads();
    if (tid == 0){
        float a0 = sh[0] + sh[1] + sh[2] + sh[3];
        float a1 = sh[4] + sh[5] + sh[6] + sh[7];
        ws[192 + t] = ws[64 + t] * 0.5f * (a0 + a1) / fmaxf(ws[128 + t], 1.f);
    }
}

__global__ void k_aux2(const float* __restrict__ ws, float* __restrict__ out){
    int l = threadIdx.x;
    float cv = ws[192 + l], sv = ws[64 + l];
    for (int m = 1; m < 64; m <<= 1){ cv += __shfl_xor(cv, m); sv += __shfl_xor(sv, m); }
    if (l == 0) out[NROWS] = (sv > 0.f) ? cv / fmaxf(sv, 1.f) : 0.f;
}

extern "C" void kernel_launch(void* const* d_in, const int* in_sizes, int n_in,
                              void* d_out, int out_size, void* d_ws, size_t ws_size,
                              hipStream_t stream) {
    const float* xc     = (const float*)d_in[0];
    const float* xs     = (const float*)d_in[1];
    const int*   labels = (const int*)d_in[2];
    const int*   mask   = (const int*)d_in[3];
    const float* ce_w1  = (const float*)d_in[4];
    const float* ce_b1  = (const float*)d_in[5];
    const float* ce_w2  = (const float*)d_in[6];
    const float* ce_b2  = (const float*)d_in[7];
    const float* se_w1  = (const float*)d_in[8];
    const float* se_b1  = (const float*)d_in[9];
    const float* se_w2  = (const float*)d_in[10];
    const float* se_b2  = (const float*)d_in[11];
    const float* cd_g   = (const float*)d_in[12];
    const float* cd_b   = (const float*)d_in[13];
    const float* cd_w1  = (const float*)d_in[14];
    const float* cd_b1  = (const float*)d_in[15];
    const float* cd_w2  = (const float*)d_in[16];
    const float* cd_b2  = (const float*)d_in[17];
    const float* jd_g   = (const float*)d_in[18];
    const float* jd_b   = (const float*)d_in[19];
    const float* jd_w1  = (const float*)d_in[20];
    const float* jd_b1  = (const float*)d_in[21];
    const float* jd_w2  = (const float*)d_in[22];
    const float* jd_b2  = (const float*)d_in[23];
    float* ws  = (float*)d_ws;
    float* out = (float*)d_out;

    k_prep<<<513, 256, 0, stream>>>(ce_w1, ce_w2, se_w1, se_w2, cd_w1, jd_w1,
                                    ce_b1, ce_b2, se_b1, se_b2, cd_g, cd_b,
                                    cd_b1, jd_g, jd_b, jd_b1, cd_w2, jd_w2,
                                    mask, labels, ws);
    k_main<<<2048, 512, 0, stream>>>(xc, xs, labels, mask, cd_b2, jd_b2, ws, out);
    k_aux1<<<64, 256, 0, stream>>>(ws);
    k_aux2<<<1, 64, 0, stream>>>(ws, out);
}